// Round 10
// baseline (2513.846 us; speedup 1.0000x reference)
//
#include <hip/hip_runtime.h>

#define ATOM  14
#define BOND  3
#define INNER 20
#define HID   34
#define REC   20
#define OHID  25
#define NN    1048576
#define NE    983040
#define NG    16384
#define NBIN  32            // bin = 2*depth + (leaf?1:0)
#define LVL_CAP 131072      // max nodes per depth (mean 65536, 2x safety)

#define NB    512
#define NT    256
#define GT    (NB*NT)       // 131072
#define SPAN  (NN/NB)       // 2048
#define SE    (SPAN/NT)     // 8

__device__ __forceinline__ float leaky(float x) { return x >= 0.f ? x : 0.01f * x; }

// grid-wide barrier: device-scope counter + fences (cross-XCD safe)
__device__ __forceinline__ void gbar(int* bar, int goal) {
    __syncthreads();
    if (threadIdx.x == 0) {
        __threadfence();
        __hip_atomic_fetch_add(bar, 1, __ATOMIC_RELEASE, __HIP_MEMORY_SCOPE_AGENT);
        while (__hip_atomic_load(bar, __ATOMIC_RELAXED, __HIP_MEMORY_SCOPE_AGENT) < goal)
            __builtin_amdgcn_s_sleep(32);
        __threadfence();
    }
    __syncthreads();
}

__global__ void k_pre(int* cnt_n, int* pp_s, float* g, int* cnt32, int* adj_total, int* bars) {
    int tid = blockIdx.x * 256 + threadIdx.x;           // 1024 blocks -> 262144 threads
    for (int i = tid; i < NN; i += 262144) { cnt_n[i] = 0; pp_s[i] = -1; }
    for (int i = tid; i < NG * REC; i += 262144) g[i] = 0.f;
    if (tid < NBIN) cnt32[tid << 4] = 0;
    if (tid == NBIN) *adj_total = 0;
    if (tid == NBIN + 1) { bars[0] = 0; bars[16] = 0; }
}

// ---------------- prep: counts, sort, CSR ----------------
__global__ __launch_bounds__(NT) void k_prep(
    const int* __restrict__ parent, const int* __restrict__ child,
    const int* __restrict__ depth, const int* __restrict__ gid,
    const float* __restrict__ isr, const float* __restrict__ bond,
    int* cnt_n, int* node_list, int* inv, int* groot_s, int* cnt_s,
    int* row_ptr, int* cur, int* pp_s, int* adjc, float4* bond_s4,
    int* cnt32, int* blkbase, int* adj_total, int* bar)
{
    __shared__ int sh[NT];
    __shared__ int soff[NBIN + 1];
    __shared__ int lh[NBIN];
    __shared__ int lbase[NBIN];
    __shared__ int sbase;
    const int t = threadIdx.x;
    const int tid = blockIdx.x * NT + t;
    const int span0 = blockIdx.x * SPAN;
    int ep = 0;

    // P0: per-node child counts (THE scattered RMW pass #1)
    for (int e = tid; e < NE; e += GT) atomicAdd(&cnt_n[parent[e]], 1);
    gbar(bar, NB * ++ep);

    // P1: per-block depth-major histogram; one global atomic per (block,bin)
    if (t < NBIN) lh[t] = 0;
    __syncthreads();
    for (int i = span0 + t; i < span0 + SPAN; i += NT) {
        int b = 2 * depth[i] + (cnt_n[i] == 0 ? 1 : 0);
        atomicAdd(&lh[b], 1);
    }
    __syncthreads();
    if (t < NBIN) blkbase[blockIdx.x * NBIN + t] = atomicAdd(&cnt32[t << 4], lh[t]);
    gbar(bar, NB * ++ep);

    // P2: scatter (counting sort); per-position metadata written at pos
    if (t == 0) {
        int s = 0;
        for (int b = 0; b < NBIN; ++b) { soff[b] = s; s += cnt32[b << 4]; }
        soff[NBIN] = s;
    }
    if (t < NBIN) { lbase[t] = blkbase[blockIdx.x * NBIN + t]; lh[t] = 0; }
    __syncthreads();
    for (int i = span0 + t; i < span0 + SPAN; i += NT) {
        int cn = cnt_n[i];
        int b = 2 * depth[i] + (cn == 0 ? 1 : 0);
        int r = atomicAdd(&lh[b], 1);
        int pos = soff[b] + lbase[b] + r;
        node_list[pos] = i;
        inv[i] = pos;
        groot_s[pos] = (isr[i] != 0.f) ? gid[i] : -1;
        cnt_s[pos] = cn;
    }
    gbar(bar, NB * ++ep);

    // P3: row_ptr via span-local scan + orderless global base; cur = copy
    {
        int base0 = span0 + t * SE;
        int v[SE]; int sum = 0;
        #pragma unroll
        for (int k = 0; k < SE; ++k) { v[k] = cnt_s[base0 + k]; sum += v[k]; }
        sh[t] = sum;
        __syncthreads();
        for (int ofs = 1; ofs < NT; ofs <<= 1) {
            int x = (t >= ofs) ? sh[t - ofs] : 0;
            __syncthreads();
            sh[t] += x;
            __syncthreads();
        }
        if (t == NT - 1) sbase = atomicAdd(adj_total, sh[t]);
        __syncthreads();
        int run = sbase + sh[t] - sum;
        #pragma unroll
        for (int k = 0; k < SE; ++k) { row_ptr[base0 + k] = run; cur[base0 + k] = run; run += v[k]; }
    }
    gbar(bar, NB * ++ep);

    // P4: edge pass 2 — adjc direct fill + per-child data (scattered pass #2)
    for (int e = tid; e < NE; e += GT) {
        int cpos = inv[child[e]];
        int pp   = inv[parent[e]];
        int slot = atomicAdd(&cur[pp], 1);
        adjc[slot] = cpos;
        pp_s[cpos] = pp;
        bond_s4[cpos] = make_float4(bond[(size_t)e * BOND], bond[(size_t)e * BOND + 1],
                                    bond[(size_t)e * BOND + 2], 0.f);
    }
}

// ---------------- levels: 16 depth phases, msg double-buffer ----------------
__device__ __forceinline__ void emit(int pos, int slot, int pp, int gr,
                                     const float* __restrict__ o,
                                     const float4* __restrict__ bond_s4,
                                     const float* __restrict__ iw,
                                     const float* __restrict__ ib,
                                     float* __restrict__ g, float* __restrict__ wbuf) {
    if (gr >= 0) {
        float* gp = g + (size_t)gr * REC;
        #pragma unroll
        for (int j = 0; j < REC; ++j) atomicAdd(&gp[j], o[j]);
    }
    if (pp >= 0) {
        float4 b4 = bond_s4[pos];
        float m[INNER];
        #pragma unroll
        for (int j = 0; j < INNER; ++j)
            m[j] = ib[j] + b4.x * iw[0 * INNER + j] + b4.y * iw[1 * INNER + j]
                         + b4.z * iw[2 * INNER + j];
        #pragma unroll
        for (int k = 0; k < REC; ++k) {
            float ok = o[k];
            #pragma unroll
            for (int j = 0; j < INNER; ++j) m[j] += ok * iw[(BOND + k) * INNER + j];
        }
        float4* mp = (float4*)(wbuf + (size_t)slot * REC);
        #pragma unroll
        for (int j = 0; j < 5; ++j)
            mp[j] = make_float4(leaky(m[4*j]), leaky(m[4*j+1]),
                                leaky(m[4*j+2]), leaky(m[4*j+3]));
    }
}

__global__ __launch_bounds__(NT) void k_levels(
    const float* __restrict__ atom,
    const int* __restrict__ node_list, const int* __restrict__ pp_s,
    const int* __restrict__ groot_s, const int* __restrict__ cnt_s,
    const int* __restrict__ row_ptr, const int* __restrict__ adjc,
    const float4* __restrict__ bond_s4,
    const float* __restrict__ iw, const float* __restrict__ ib,
    const float* __restrict__ nw1, const float* __restrict__ nb1,
    const float* __restrict__ nw2, const float* __restrict__ nb2,
    const float* __restrict__ l0w1, const float* __restrict__ l0b1,
    const float* __restrict__ l0w2, const float* __restrict__ l0b2,
    float* __restrict__ g, float* buf0, float* buf1,
    const int* __restrict__ cnt32, int* bar)
{
    __shared__ int soff[NBIN + 1];
    const int t = threadIdx.x;
    const int tid = blockIdx.x * NT + t;
    int ep = 0;
    if (t == 0) {
        int s = 0;
        for (int b = 0; b < NBIN; ++b) { soff[b] = s; s += cnt32[b << 4]; }
        soff[NBIN] = s;
    }
    __syncthreads();

    for (int D = 15; D >= 0; --D) {
        int base = soff[2 * D];
        int limI = soff[2 * D + 1];
        int limA = soff[2 * D + 2];
        int cbase = (D < 15) ? soff[2 * D + 2] : 0;   // children-depth base
        float* wbuf = (D & 1) ? buf1 : buf0;
        const float* rbuf = (D & 1) ? buf0 : buf1;

        // internal nodes at depth D (uniform waves)
        for (int pos = base + tid; pos < limI; pos += GT) {
            int n   = cnt_s[pos];
            int i   = node_list[pos];
            int pp  = pp_s[pos];
            int gr  = groot_s[pos];
            int rp0 = row_ptr[pos];
            const float2* a2 = (const float2*)(atom + (size_t)i * ATOM);
            float a[ATOM];
            #pragma unroll
            for (int k = 0; k < 7; ++k) { float2 v = a2[k]; a[2*k] = v.x; a[2*k+1] = v.y; }
            float isum[INNER];
            #pragma unroll
            for (int j = 0; j < INNER; ++j) isum[j] = 0.f;
            {
                int rp1 = rp0 + n;
                int nm1 = n - 1;
                int k1 = nm1 < 1 ? nm1 : 1;
                int k2 = nm1 < 2 ? nm1 : 2;
                int k3 = nm1 < 3 ? nm1 : 3;
                int c0 = adjc[rp0]      - cbase;
                int c1 = adjc[rp0 + k1] - cbase;
                int c2 = adjc[rp0 + k2] - cbase;
                int c3 = adjc[rp0 + k3] - cbase;
                float f1 = n > 1 ? 1.f : 0.f;
                float f2 = n > 2 ? 1.f : 0.f;
                float f3 = n > 3 ? 1.f : 0.f;
                const float4* p0 = (const float4*)(rbuf + (size_t)c0 * REC);
                const float4* p1 = (const float4*)(rbuf + (size_t)c1 * REC);
                const float4* p2 = (const float4*)(rbuf + (size_t)c2 * REC);
                const float4* p3 = (const float4*)(rbuf + (size_t)c3 * REC);
                #pragma unroll
                for (int q = 0; q < 5; ++q) {
                    float4 v0 = p0[q], v1 = p1[q], v2 = p2[q], v3 = p3[q];
                    isum[4*q]   += v0.x + f1 * v1.x + f2 * v2.x + f3 * v3.x;
                    isum[4*q+1] += v0.y + f1 * v1.y + f2 * v2.y + f3 * v3.y;
                    isum[4*q+2] += v0.z + f1 * v1.z + f2 * v2.z + f3 * v3.z;
                    isum[4*q+3] += v0.w + f1 * v1.w + f2 * v2.w + f3 * v3.w;
                }
                for (int r = rp0 + 4; r < rp1; ++r) {
                    int c = adjc[r] - cbase;
                    const float4* mp = (const float4*)(rbuf + (size_t)c * REC);
                    #pragma unroll
                    for (int q = 0; q < 5; ++q) {
                        float4 v = mp[q];
                        isum[4*q]   += v.x; isum[4*q+1] += v.y;
                        isum[4*q+2] += v.z; isum[4*q+3] += v.w;
                    }
                }
            }
            float hid[HID];
            #pragma unroll
            for (int j = 0; j < HID; ++j) hid[j] = nb1[j];
            for (int k = 0; k < ATOM; ++k) {
                float xk = a[k];
                #pragma unroll
                for (int j = 0; j < HID; ++j) hid[j] += xk * nw1[k * HID + j];
            }
            for (int k = 0; k < INNER; ++k) {
                float xk = isum[k];
                #pragma unroll
                for (int j = 0; j < HID; ++j) hid[j] += xk * nw1[(ATOM + k) * HID + j];
            }
            #pragma unroll
            for (int j = 0; j < HID; ++j) hid[j] = leaky(hid[j]);
            float o[REC];
            #pragma unroll
            for (int j = 0; j < REC; ++j) o[j] = nb2[j];
            for (int k = 0; k < HID; ++k) {
                float hk = hid[k];
                #pragma unroll
                for (int j = 0; j < REC; ++j) o[j] += hk * nw2[k * REC + j];
            }
            #pragma unroll
            for (int j = 0; j < REC; ++j) o[j] = leaky(o[j]);
            emit(pos, pos - base, pp, gr, o, bond_s4, iw, ib, g, wbuf);
        }

        // leaves at depth D (uniform waves)
        for (int pos = limI + tid; pos < limA; pos += GT) {
            int i  = node_list[pos];
            int pp = pp_s[pos];
            int gr = groot_s[pos];
            const float2* a2 = (const float2*)(atom + (size_t)i * ATOM);
            float a[ATOM];
            #pragma unroll
            for (int k = 0; k < 7; ++k) { float2 v = a2[k]; a[2*k] = v.x; a[2*k+1] = v.y; }
            float hid[HID];
            #pragma unroll
            for (int j = 0; j < HID; ++j) hid[j] = l0b1[j];
            for (int k = 0; k < ATOM; ++k) {
                float ak = a[k];
                #pragma unroll
                for (int j = 0; j < HID; ++j) hid[j] += ak * l0w1[k * HID + j];
            }
            #pragma unroll
            for (int j = 0; j < HID; ++j) hid[j] = leaky(hid[j]);
            float o[REC];
            #pragma unroll
            for (int j = 0; j < REC; ++j) o[j] = l0b2[j];
            for (int k = 0; k < HID; ++k) {
                float hk = hid[k];
                #pragma unroll
                for (int j = 0; j < REC; ++j) o[j] += hk * l0w2[k * REC + j];
            }
            #pragma unroll
            for (int j = 0; j < REC; ++j) o[j] = leaky(o[j]);
            emit(pos, pos - base, pp, gr, o, bond_s4, iw, ib, g, wbuf);
        }
        if (D) gbar(bar, NB * ++ep);
    }
}

// ---------------- readout ----------------
__global__ void k_out(const float* __restrict__ g,
                      const float* __restrict__ w1, const float* __restrict__ b1,
                      const float* __restrict__ w2, const float* __restrict__ b2,
                      float* __restrict__ out) {
    int t = blockIdx.x * 256 + threadIdx.x;
    if (t >= NG) return;
    const float* gv = g + (size_t)t * REC;
    float gl[REC];
    #pragma unroll
    for (int k = 0; k < REC; ++k) gl[k] = gv[k];
    float acc = b2[0];
    for (int j = 0; j < OHID; ++j) {
        float s = b1[j];
        #pragma unroll
        for (int k = 0; k < REC; ++k) s += gl[k] * w1[k * OHID + j];
        acc += tanhf(s) * w2[j];
    }
    out[t] = acc;
}

extern "C" void kernel_launch(void* const* d_in, const int* in_sizes, int n_in,
                              void* d_out, int out_size, void* d_ws, size_t ws_size,
                              hipStream_t stream) {
    const float* atom    = (const float*)d_in[0];
    const float* bond    = (const float*)d_in[1];
    const int*   parent  = (const int*)d_in[2];
    const int*   child   = (const int*)d_in[3];
    const int*   depth   = (const int*)d_in[4];
    const int*   gid     = (const int*)d_in[5];
    const float* isr     = (const float*)d_in[6];
    const float* inner_w = (const float*)d_in[7];
    const float* inner_b = (const float*)d_in[8];
    const float* net_w1  = (const float*)d_in[9];
    const float* net_b1  = (const float*)d_in[10];
    const float* net_w2  = (const float*)d_in[11];
    const float* net_b2  = (const float*)d_in[12];
    const float* net0_w1 = (const float*)d_in[13];
    const float* net0_b1 = (const float*)d_in[14];
    const float* net0_w2 = (const float*)d_in[15];
    const float* net0_b2 = (const float*)d_in[16];
    const float* out_w1  = (const float*)d_in[17];
    const float* out_b1  = (const float*)d_in[18];
    const float* out_w2  = (const float*)d_in[19];
    const float* out_b2  = (const float*)d_in[20];
    float* out = (float*)d_out;

    char* ws = (char*)d_ws;
    size_t o = 0;
    float* buf0     = (float*)(ws + o);  o += (size_t)LVL_CAP * REC * 4;  // 10.5 MB
    float* buf1     = (float*)(ws + o);  o += (size_t)LVL_CAP * REC * 4;  // 10.5 MB
    float* g        = (float*)(ws + o);  o += (size_t)NG * REC * 4;       // 1.3 MB
    float4* bond_s4 = (float4*)(ws + o); o += (size_t)NN * 16;            // 16.8 MB
    int* cnt_n      = (int*)(ws + o);    o += (size_t)NN * 4;             // 4.2 MB
    int* node_list  = (int*)(ws + o);    o += (size_t)NN * 4;
    int* inv        = (int*)(ws + o);    o += (size_t)NN * 4;
    int* groot_s    = (int*)(ws + o);    o += (size_t)NN * 4;
    int* cnt_s      = (int*)(ws + o);    o += (size_t)NN * 4;
    int* row_ptr    = (int*)(ws + o);    o += (size_t)NN * 4;
    int* cur        = (int*)(ws + o);    o += (size_t)NN * 4;
    int* pp_s       = (int*)(ws + o);    o += (size_t)NN * 4;
    int* adjc       = (int*)(ws + o);    o += (size_t)NE * 4;             // 3.9 MB
    int* blkbase    = (int*)(ws + o);    o += (size_t)NB * NBIN * 4;      // 64 KB
    int* cnt32      = (int*)(ws + o);    o += NBIN * 16 * 4;
    int* adj_total  = (int*)(ws + o);    o += 64;
    int* bars       = (int*)(ws + o);    o += 256;
    // total ~78 MB

    k_pre<<<1024, 256, 0, stream>>>(cnt_n, pp_s, g, cnt32, adj_total, bars);
    k_prep<<<NB, NT, 0, stream>>>(parent, child, depth, gid, isr, bond,
                                  cnt_n, node_list, inv, groot_s, cnt_s,
                                  row_ptr, cur, pp_s, adjc, bond_s4,
                                  cnt32, blkbase, adj_total, &bars[0]);
    k_levels<<<NB, NT, 0, stream>>>(atom, node_list, pp_s, groot_s, cnt_s,
                                    row_ptr, adjc, bond_s4,
                                    inner_w, inner_b, net_w1, net_b1, net_w2, net_b2,
                                    net0_w1, net0_b1, net0_w2, net0_b2,
                                    g, buf0, buf1, cnt32, &bars[16]);
    k_out<<<(NG + 255) / 256, 256, 0, stream>>>(g, out_w1, out_b1, out_w2, out_b2, out);
}